// Round 4
// baseline (450.001 us; speedup 1.0000x reference)
//
#include <hip/hip_runtime.h>
#include <hip/hip_fp16.h>
#include <math.h>

#define N_NODES 100000
#define N_EDGES 1600000
#define NPW 8  // nodes per wave in k_agg1; 32/block; 100000/32 = 3125 exact

// ================= CSR build (by dst) =================

__global__ void k_count(const int* __restrict__ dst, int* __restrict__ cnt, int e) {
    int i = (blockIdx.x * blockDim.x + threadIdx.x) * 4;
    if (i + 3 < e) {
        int4 d4 = *(const int4*)(dst + i);
        atomicAdd(&cnt[d4.x], 1);
        atomicAdd(&cnt[d4.y], 1);
        atomicAdd(&cnt[d4.z], 1);
        atomicAdd(&cnt[d4.w], 1);
    } else {
        for (; i < e; ++i) atomicAdd(&cnt[dst[i]], 1);
    }
}

// scanA: per-block exclusive scan of 1024 ints (4/thread); also dinv = rsqrt(deg+1)
__global__ void k_scanA(const int* __restrict__ cnt, int* __restrict__ off,
                        int* __restrict__ bsums, float* __restrict__ dinv, int n) {
    __shared__ int sd[256];
    int t = threadIdx.x;
    int base = blockIdx.x * 1024 + t * 4;
    int e0 = (base + 0 < n) ? cnt[base + 0] : 0;
    int e1 = (base + 1 < n) ? cnt[base + 1] : 0;
    int e2 = (base + 2 < n) ? cnt[base + 2] : 0;
    int e3 = (base + 3 < n) ? cnt[base + 3] : 0;
    if (base + 0 < n) dinv[base + 0] = rsqrtf((float)e0 + 1.0f);
    if (base + 1 < n) dinv[base + 1] = rsqrtf((float)e1 + 1.0f);
    if (base + 2 < n) dinv[base + 2] = rsqrtf((float)e2 + 1.0f);
    if (base + 3 < n) dinv[base + 3] = rsqrtf((float)e3 + 1.0f);
    int s = e0 + e1 + e2 + e3;
    sd[t] = s;
    __syncthreads();
    for (int o = 1; o < 256; o <<= 1) {
        int v = (t >= o) ? sd[t - o] : 0;
        __syncthreads();
        sd[t] += v;
        __syncthreads();
    }
    int excl = sd[t] - s;
    if (base + 0 < n) off[base + 0] = excl;
    if (base + 1 < n) off[base + 1] = excl + e0;
    if (base + 2 < n) off[base + 2] = excl + e0 + e1;
    if (base + 3 < n) off[base + 3] = excl + e0 + e1 + e2;
    if (t == 0) bsums[blockIdx.x] = sd[255];
}

__global__ void k_scanB(int* __restrict__ bsums, int* __restrict__ off, int nb, int n) {
    __shared__ int sd[128];
    int t = threadIdx.x;
    int v = (t < nb) ? bsums[t] : 0;
    sd[t] = v;
    __syncthreads();
    for (int o = 1; o < 128; o <<= 1) {
        int u = (t >= o) ? sd[t - o] : 0;
        __syncthreads();
        sd[t] += u;
        __syncthreads();
    }
    if (t < nb) bsums[t] = sd[t] - v;
    if (t == 127) off[n] = sd[127];
}

__global__ void k_scanC(int* __restrict__ off, int* __restrict__ cursor,
                        const int* __restrict__ bsums, int n) {
    int i = blockIdx.x * blockDim.x + threadIdx.x;
    if (i < n) {
        int v = off[i] + bsums[i >> 10];
        off[i] = v;
        cursor[i] = v;
    }
}

__global__ void k_fill(const int* __restrict__ src, const int* __restrict__ dst,
                       int* __restrict__ cursor, int* __restrict__ csr, int e) {
    int i = (blockIdx.x * blockDim.x + threadIdx.x) * 4;
    if (i + 3 < e) {
        int4 s4 = *(const int4*)(src + i);
        int4 d4 = *(const int4*)(dst + i);
        csr[atomicAdd(&cursor[d4.x], 1)] = s4.x;
        csr[atomicAdd(&cursor[d4.y], 1)] = s4.y;
        csr[atomicAdd(&cursor[d4.z], 1)] = s4.z;
        csr[atomicAdd(&cursor[d4.w], 1)] = s4.w;
    } else {
        for (; i < e; ++i) csr[atomicAdd(&cursor[dst[i]], 1)] = src[i];
    }
}

// ======== conv: xh[s][f] = (half)(x[s][f] * dinv[s]) — folds per-src norm ========
// grid covers n*16 float4s exactly (100000*16/256 = 6250 blocks).

__global__ void k_conv(const float* __restrict__ x, const float* __restrict__ dinv,
                       __half2* __restrict__ xh) {
    int t = blockIdx.x * blockDim.x + threadIdx.x;  // float4 index
    const float4* x4 = (const float4*)x;
    float4 v = x4[t];
    float di = dinv[t >> 4];
    __half2 h0 = __floats2half2_rn(v.x * di, v.y * di);
    __half2 h1 = __floats2half2_rn(v.z * di, v.w * di);
    xh[t * 2 + 0] = h0;
    xh[t * 2 + 1] = h1;
}

// ======== Fused layer-1 + GEMM1 + GEMM2: h2s = relu((A_hat X) W1 + b1) @ W2 * dinv ========
// 4 waves/block, NPW nodes/wave. Gather: lane = 32*h + m; lane reads half2 =
// feats (2m,2m+1); halves handle edges j / j+1 => one 256B wave load = 2 edges,
// 8-way unroll = 8 edges in flight, inner op is a bare add (dinv folded in xh).
// Phase B/C use wave-local LDS rows (no barriers after the staging one).

__global__ __launch_bounds__(256, 7) void k_agg1(
        const __half2* __restrict__ xh, const int* __restrict__ off,
        const int* __restrict__ csr, const float* __restrict__ dinv,
        const float* __restrict__ W1, const float* __restrict__ W2,
        const float* __restrict__ b1, float* __restrict__ h2s, int n) {
    __shared__ float W1s[64 * 64];
    __shared__ float W2s[64 * 17];   // padded
    __shared__ float xsw[4][64];     // per-wave aggregated row
    __shared__ float vsw[4][64];     // per-wave relu row
    int tid = threadIdx.x;
    {
        const float4* W14 = (const float4*)W1;
        float4* W1s4 = (float4*)W1s;
#pragma unroll
        for (int i = 0; i < 4; ++i) W1s4[tid + 256 * i] = W14[tid + 256 * i];
        for (int i = tid; i < 64 * 16; i += 256) W2s[(i >> 4) * 17 + (i & 15)] = W2[i];
    }
    __syncthreads();  // only block-wide barrier

    int w = tid >> 6, lane = tid & 63;
    int h = lane >> 5, m = lane & 31;
    int f = lane;
    int q = lane >> 4, c = lane & 15;
    float b1f = b1[f];

    int base = blockIdx.x * (4 * NPW) + w * NPW;
#pragma unroll 1
    for (int nn = 0; nn < NPW; ++nn) {
        int d = base + nn;  // grid covers n exactly
        float dd = dinv[d];
        float2 svf = __half22float2(xh[(size_t)d * 32 + m]);  // = x[d]*dinv[d]
        float ax = (h == 0) ? svf.x : 0.f;
        float ay = (h == 0) ? svf.y : 0.f;
        int j = off[d], je = off[d + 1];
        for (; j + 8 <= je; j += 8) {
            int s0 = csr[j + h], s1 = csr[j + 2 + h];
            int s2 = csr[j + 4 + h], s3 = csr[j + 6 + h];
            float2 v0 = __half22float2(xh[(size_t)s0 * 32 + m]);
            float2 v1 = __half22float2(xh[(size_t)s1 * 32 + m]);
            float2 v2 = __half22float2(xh[(size_t)s2 * 32 + m]);
            float2 v3 = __half22float2(xh[(size_t)s3 * 32 + m]);
            ax += (v0.x + v1.x) + (v2.x + v3.x);
            ay += (v0.y + v1.y) + (v2.y + v3.y);
        }
        for (; j + 2 <= je; j += 2) {
            int s0 = csr[j + h];
            float2 v0 = __half22float2(xh[(size_t)s0 * 32 + m]);
            ax += v0.x; ay += v0.y;
        }
        if (j < je && h == 0) {  // odd leftover edge: half 0 only
            int s0 = csr[j];
            float2 v0 = __half22float2(xh[(size_t)s0 * 32 + m]);
            ax += v0.x; ay += v0.y;
        }
        ax += __shfl_xor(ax, 32);
        ay += __shfl_xor(ay, 32);
        if (h == 0) ((float2*)xsw[w])[m] = make_float2(ax * dd, ay * dd);
        // Phase B: out1[f] = b1[f] + sum_k agg[k]*W1[k][f]; relu
        float accB = b1f;
        const float4* xw4 = (const float4*)xsw[w];
#pragma unroll
        for (int k4 = 0; k4 < 16; ++k4) {
            float4 xv = xw4[k4];
            accB = fmaf(xv.x, W1s[(k4 * 4 + 0) * 64 + f], accB);
            accB = fmaf(xv.y, W1s[(k4 * 4 + 1) * 64 + f], accB);
            accB = fmaf(xv.z, W1s[(k4 * 4 + 2) * 64 + f], accB);
            accB = fmaf(xv.w, W1s[(k4 * 4 + 3) * 64 + f], accB);
        }
        vsw[w][f] = fmaxf(accB, 0.f);
        // Phase C: h2[d][c] = sum_k v[k]*W2[k][c]; store * dinv[d] (fold for agg2)
        float p = 0.f;
        const float4* vw4 = (const float4*)vsw[w];
#pragma unroll
        for (int kk4 = 0; kk4 < 4; ++kk4) {
            float4 vv = vw4[q * 4 + kk4];
            p = fmaf(vv.x, W2s[(q * 16 + kk4 * 4 + 0) * 17 + c], p);
            p = fmaf(vv.y, W2s[(q * 16 + kk4 * 4 + 1) * 17 + c], p);
            p = fmaf(vv.z, W2s[(q * 16 + kk4 * 4 + 2) * 17 + c], p);
            p = fmaf(vv.w, W2s[(q * 16 + kk4 * 4 + 3) * 17 + c], p);
        }
        p += __shfl_xor(p, 16);
        p += __shfl_xor(p, 32);
        if (lane < 16) h2s[(size_t)d * 16 + lane] = p * dd;
    }
}

// ======== Layer-2 aggregation + b2 + log_softmax ========
// 4 waves/block, 1 node/wave; lane = 16*g + c; groups stride edges; inner op
// is a bare add (dinv folded into h2s).

__global__ __launch_bounds__(256, 8) void k_agg2_lsm(
        const float* __restrict__ h2s, const int* __restrict__ off,
        const int* __restrict__ csr, const float* __restrict__ dinv,
        const float* __restrict__ b2, float* __restrict__ y, int n) {
    int tid = threadIdx.x;
    int w = tid >> 6, lane = tid & 63, g = lane >> 4, c = lane & 15;
    int d = blockIdx.x * 4 + w;
    if (d >= n) return;
    float dd = dinv[d];
    float acc0 = (g == 0) ? h2s[(size_t)d * 16 + c] : 0.f;  // self (pre-folded)
    float acc1 = 0.f;
    int j = off[d], je = off[d + 1];
    for (; j + 8 <= je; j += 8) {
        int sA = csr[j + g], sB = csr[j + 4 + g];
        acc0 += h2s[(size_t)sA * 16 + c];
        acc1 += h2s[(size_t)sB * 16 + c];
    }
    for (; j < je; j += 4) {
        if (j + g < je) {
            int s = csr[j + g];
            acc0 += h2s[(size_t)s * 16 + c];
        }
    }
    float acc = acc0 + acc1;
    acc += __shfl_xor(acc, 16);
    acc += __shfl_xor(acc, 32);
    float v = acc * dd + b2[c];
    float mx = v;
#pragma unroll
    for (int o = 1; o < 16; o <<= 1) mx = fmaxf(mx, __shfl_xor(mx, o));
    float ssum = expf(v - mx);
#pragma unroll
    for (int o = 1; o < 16; o <<= 1) ssum += __shfl_xor(ssum, o);
    float r = v - (logf(ssum) + mx);
    if (g == 0) y[(size_t)d * 16 + c] = r;
}

// ================= launcher =================

extern "C" void kernel_launch(void* const* d_in, const int* in_sizes, int n_in,
                              void* d_out, int out_size, void* d_ws, size_t ws_size,
                              hipStream_t stream) {
    const float* x  = (const float*)d_in[0];
    const int*   ei = (const int*)d_in[1];          // [2, E] row-major
    const float* W1 = (const float*)d_in[2];
    const float* b1 = (const float*)d_in[3];
    const float* W2 = (const float*)d_in[4];
    const float* b2 = (const float*)d_in[5];
    float* y = (float*)d_out;

    const int n = N_NODES;
    const int e = N_EDGES;
    const int* src = ei;
    const int* dst = ei + e;

    // workspace layout (4-byte units); total ~27.3 MB
    float* ws = (float*)d_ws;
    int*     cnt    = (int*)ws;                      // n
    float*   dinv   = ws + 102400;                   // n
    int*     off    = (int*)(ws + 204800);           // n+1
    int*     cursor = (int*)(ws + 307200);           // n
    int*     bsums  = (int*)(ws + 409600);           // <=128
    int*     csr    = (int*)(ws + 410624);           // e
    __half2* xh     = (__half2*)(ws + 410624 + 1600000);  // n*64 halves (12.8MB), 16B-aligned
    float*   h2s    = ws + 410624 + 1600000 + 3200000;    // n*16

    const int nb = (n + 1023) / 1024;                // 98

    hipMemsetAsync(cnt, 0, (size_t)n * sizeof(int), stream);
    k_count<<<(e / 4 + 255) / 256, 256, 0, stream>>>(dst, cnt, e);
    k_scanA<<<nb, 256, 0, stream>>>(cnt, off, bsums, dinv, n);
    k_scanB<<<1, 128, 0, stream>>>(bsums, off, nb, n);
    k_scanC<<<(n + 255) / 256, 256, 0, stream>>>(off, cursor, bsums, n);
    k_fill <<<(e / 4 + 255) / 256, 256, 0, stream>>>(src, dst, cursor, csr, e);

    k_conv<<<n * 16 / 256, 256, 0, stream>>>(x, dinv, xh);            // 6250 blocks
    k_agg1<<<n / (4 * NPW), 256, 0, stream>>>(xh, off, csr, dinv, W1, W2, b1, h2s, n);  // 3125
    k_agg2_lsm<<<(n + 3) / 4, 256, 0, stream>>>(h2s, off, csr, dinv, b2, y, n);
}